// Round 4
// baseline (24.751 us; speedup 1.0000x reference)
//
#include <hip/hip_runtime.h>
#include <math.h>

#define NPTS 200
#define L33   33
#define L33SQ 1089        // 33*33
#define NLAT  35937       // 33^3
#define NCELL 32768       // 32^3
// ws layout: [0, 1MB) per-cell packed corners (float4 pairs); [1MB, +144KB) scalar T lattice
#define T_OFF_FLOATS (NCELL * 8)

// ---------- trilinear label (channel 0) of grid g at u in [0,R]^3 ----------
template<int R>
__device__ __forceinline__ float tri_label(const float* __restrict__ g,
                                           float ux, float uy, float uz) {
    constexpr int Rp1 = R + 1;
    constexpr int SX  = Rp1 * Rp1;
    int ix = min((int)ux, R - 1);
    int iy = min((int)uy, R - 1);
    int iz = min((int)uz, R - 1);
    float fx = ux - (float)ix, fy = uy - (float)iy, fz = uz - (float)iz;
    int b = (ix * Rp1 + iy) * Rp1 + iz;
    float v000 = g[4*b],            v001 = g[4*(b+1)];
    float v010 = g[4*(b+Rp1)],      v011 = g[4*(b+Rp1+1)];
    float v100 = g[4*(b+SX)],       v101 = g[4*(b+SX+1)];
    float v110 = g[4*(b+SX+Rp1)],   v111 = g[4*(b+SX+Rp1+1)];
    float c00 = fmaf(fz, v001 - v000, v000);
    float c01 = fmaf(fz, v011 - v010, v010);
    float c10 = fmaf(fz, v101 - v100, v100);
    float c11 = fmaf(fz, v111 - v110, v110);
    float c0  = fmaf(fy, c01 - c00, c00);
    float c1  = fmaf(fy, c11 - c10, c10);
    return fmaf(fx, c1 - c0, c0);
}

// ---------- prep1: combined logit field at every 33^3 lattice point ----------
__global__ __launch_bounds__(256)
void prep1_kernel(const float* __restrict__ g0, const float* __restrict__ g1,
                  const float* __restrict__ g2, const float* __restrict__ wl,
                  const float* __restrict__ bl, float* __restrict__ T) {
    int i = blockIdx.x * blockDim.x + threadIdx.x;
    if (i >= NLAT) return;
    int jz = i % L33;
    int r  = i / L33;
    int jy = r % L33;
    int jx = r / L33;
    float fx = (float)jx, fy = (float)jy, fz = (float)jz;
    float L0 = tri_label<8 >(g0, fx * 0.25f, fy * 0.25f, fz * 0.25f);  // exact quarters
    float L1 = tri_label<16>(g1, fx * 0.5f,  fy * 0.5f,  fz * 0.5f);   // exact halves
    float L2 = g2[4 * i];
    T[i] = bl[0] + wl[0] * L0 + wl[1] * L1 + wl[2] * L2;
}

// ---------- prep2: pack 8 corners per 32^3 cell, 32B-aligned ----------
// C[2*cell+0] = {T(x0,y0,z0), T(x0,y0,z1), T(x0,y1,z0), T(x0,y1,z1)}
// C[2*cell+1] = same with x1
__global__ __launch_bounds__(256)
void prep2_kernel(const float* __restrict__ T, float4* __restrict__ C) {
    int i = blockIdx.x * blockDim.x + threadIdx.x;
    if (i >= NCELL) return;
    int iz = i & 31;
    int iy = (i >> 5) & 31;
    int ix = i >> 10;
    int b = (ix * L33 + iy) * L33 + iz;
    float4 a, c;
    a.x = T[b];            a.y = T[b + 1];
    a.z = T[b + L33];      a.w = T[b + L33 + 1];
    c.x = T[b + L33SQ];        c.y = T[b + L33SQ + 1];
    c.z = T[b + L33SQ + L33];  c.w = T[b + L33SQ + L33 + 1];
    C[2 * i]     = a;
    C[2 * i + 1] = c;
}

// ---------- RGB corner contribution (1 point per ray, corner-parallel) ----------
template<int R>
__device__ __forceinline__ void rgb_corner(const float* __restrict__ g,
                                           float cx, float cy, float cz,
                                           int dx, int dy, int dz,
                                           float* f3) {
    constexpr int Rp1 = R + 1;
    float ux = cx * (float)R, uy = cy * (float)R, uz = cz * (float)R;
    int ix = min((int)ux, R - 1);
    int iy = min((int)uy, R - 1);
    int iz = min((int)uz, R - 1);
    float fx = ux - (float)ix, fy = uy - (float)iy, fz = uz - (float)iz;
    int idx = ((ix + dx) * Rp1 + (iy + dy)) * Rp1 + (iz + dz);
    float w = (dx ? fx : 1.0f - fx) * (dy ? fy : 1.0f - fy) * (dz ? fz : 1.0f - fz);
    float4 v = *reinterpret_cast<const float4*>(g + 4 * idx);
    f3[0] = w * v.y;
    f3[1] = w * v.z;
    f3[2] = w * v.w;
}

// ---------- main: 8 lanes/ray, 25 CONSECUTIVE points per lane, cached cell ----------
__global__ __launch_bounds__(256)
void rays_kernel(const float* __restrict__ x,
                 const float4* __restrict__ C,
                 const float* __restrict__ g0,
                 const float* __restrict__ g1,
                 const float* __restrict__ g2,
                 const float* __restrict__ wr,
                 const float* __restrict__ br,
                 float* __restrict__ out_hits,
                 float* __restrict__ out_rgb,
                 int n)
{
    const int tid = blockIdx.x * blockDim.x + threadIdx.x;
    const int ray = tid >> 3;
    const int sub = (int)(threadIdx.x & 7);
    if (ray >= n) return;

    const float th1 = x[ray * 4 + 0];
    const float ph1 = x[ray * 4 + 1];
    const float th2 = x[ray * 4 + 2];
    const float ph2 = x[ray * 4 + 3];
    float s1 = __sinf(th1), c1 = __cosf(th1);
    float s2 = __sinf(th2), c2 = __cosf(th2);
    float p1x = s1 * __cosf(ph1), p1y = s1 * __sinf(ph1), p1z = c1;
    float p2x = s2 * __cosf(ph2), p2y = s2 * __sinf(ph2), p2z = c2;
    const float dxr = p2x - p1x, dyr = p2y - p1y, dzr = p2z - p1z;

    const float inv = 1.0f / (float)(NPTS - 1);
    const float sc  = 16.0f * inv;

    // u(t) = (p+1)*16 ; u in [0,32] exactly (coords in [-1,1]), no clamp needed
    const float bx = fmaf(p1x, 16.0f, 16.0f);
    const float by = fmaf(p1y, 16.0f, 16.0f);
    const float bz = fmaf(p1z, 16.0f, 16.0f);
    const float dux = dxr * sc, duy = dyr * sc, duz = dzr * sc;

    float tf = (float)(sub * 25);            // exact small ints
    float maxlogit = -INFINITY;
    int firsthit = NPTS;
    int cidx = -1;
    float4 q0 = {0.f, 0.f, 0.f, 0.f}, q1 = {0.f, 0.f, 0.f, 0.f};

    for (int i = 0; i < 25; ++i) {
        float ux = fmaf(tf, dux, bx);
        float uy = fmaf(tf, duy, by);
        float uz = fmaf(tf, duz, bz);
        int ix = min((int)ux, 31);
        int iy = min((int)uy, 31);
        int iz = min((int)uz, 31);
        float fx = ux - (float)ix;
        float fy = uy - (float)iy;
        float fz = uz - (float)iz;
        int idx = (ix << 10) + (iy << 5) + iz;
        if (idx != cidx) {                   // reload only on cell crossing
            cidx = idx;
            q0 = C[2 * idx];
            q1 = C[2 * idx + 1];
        }
        float mx = fmaf(fx, q1.x - q0.x, q0.x);
        float my = fmaf(fx, q1.y - q0.y, q0.y);
        float mz = fmaf(fx, q1.z - q0.z, q0.z);
        float mw = fmaf(fx, q1.w - q0.w, q0.w);
        float r0 = fmaf(fz, my - mx, mx);
        float r1 = fmaf(fz, mw - mz, mz);
        float logit = fmaf(fy, r1 - r0, r0);
        maxlogit = fmaxf(maxlogit, logit);
        if (logit > 0.0f) firsthit = min(firsthit, sub * 25 + i);
        tf += 1.0f;
    }

#pragma unroll
    for (int m = 4; m >= 1; m >>= 1) {
        maxlogit = fmaxf(maxlogit, __shfl_xor(maxlogit, m, 64));
        firsthit = min(firsthit, __shfl_xor(firsthit, m, 64));
    }

    // ---- RGB at first-hit point, corner-parallel across the 8 lanes ----
    const int tsel = (firsthit >= NPTS) ? 0 : firsthit;
    {
        float tt = (float)tsel * inv;
        float px = fmaf(dxr, tt, p1x);
        float py = fmaf(dyr, tt, p1y);
        float pz = fmaf(dzr, tt, p1z);
        float cx = fminf(fmaxf(fmaf(px, 0.5f, 0.5f), 0.0f), 1.0f);
        float cy = fminf(fmaxf(fmaf(py, 0.5f, 0.5f), 0.0f), 1.0f);
        float cz = fminf(fmaxf(fmaf(pz, 0.5f, 0.5f), 0.0f), 1.0f);
        const int dx = (sub >> 2) & 1, dy = (sub >> 1) & 1, dz = sub & 1;
        float feat[9];
        rgb_corner<8 >(g0, cx, cy, cz, dx, dy, dz, &feat[0]);
        rgb_corner<16>(g1, cx, cy, cz, dx, dy, dz, &feat[3]);
        rgb_corner<32>(g2, cx, cy, cz, dx, dy, dz, &feat[6]);
#pragma unroll
        for (int m = 4; m >= 1; m >>= 1) {
#pragma unroll
            for (int k = 0; k < 9; ++k)
                feat[k] += __shfl_xor(feat[k], m, 64);
        }
        if (sub == 0) {
            out_hits[ray] = 1.0f / (1.0f + __expf(-maxlogit));
#pragma unroll
            for (int c = 0; c < 3; ++c) {
                float acc = br[c];
#pragma unroll
                for (int f = 0; f < 9; ++f) acc += feat[f] * wr[f * 3 + c];
                out_rgb[ray * 3 + c] = 1.0f / (1.0f + __expf(-acc));
            }
        }
    }
}

extern "C" void kernel_launch(void* const* d_in, const int* in_sizes, int n_in,
                              void* d_out, int out_size, void* d_ws, size_t ws_size,
                              hipStream_t stream) {
    const float* x  = (const float*)d_in[0];
    const float* g0 = (const float*)d_in[1];
    const float* g1 = (const float*)d_in[2];
    const float* g2 = (const float*)d_in[3];
    const float* wl = (const float*)d_in[4];
    const float* bl = (const float*)d_in[5];
    const float* wr = (const float*)d_in[6];
    const float* br = (const float*)d_in[7];

    const int n = in_sizes[0] / 4;
    float* out_hits = (float*)d_out;
    float* out_rgb  = (float*)d_out + n;

    float4* C = (float4*)d_ws;                        // 1 MB packed cells
    float*  T = (float*)d_ws + T_OFF_FLOATS;          // 144 KB lattice

    prep1_kernel<<<(NLAT + 255) / 256, 256, 0, stream>>>(g0, g1, g2, wl, bl, T);
    prep2_kernel<<<(NCELL + 255) / 256, 256, 0, stream>>>(T, C);

    const int block = 256;       // 32 rays per block
    const int grid = (n * 8 + block - 1) / block;
    rays_kernel<<<grid, block, 0, stream>>>(x, C, g0, g1, g2, wr, br,
                                            out_hits, out_rgb, n);
}

// Round 5
// 21.354 us; speedup vs baseline: 1.1591x; 1.1591x over previous
//
#include <hip/hip_runtime.h>
#include <math.h>

#define NPTS 200
#define L33   33
#define NLAT  35937        // 33^3
#define NPREP (NLAT * 4)   // one thread per (lattice point, corner)

// ---------- trilinear label (channel 0) of grid g at u in [0,R]^3 ----------
template<int R>
__device__ __forceinline__ float tri_label(const float* __restrict__ g,
                                           float ux, float uy, float uz) {
    constexpr int Rp1 = R + 1;
    constexpr int SX  = Rp1 * Rp1;
    int ix = min((int)ux, R - 1);
    int iy = min((int)uy, R - 1);
    int iz = min((int)uz, R - 1);
    float fx = ux - (float)ix, fy = uy - (float)iy, fz = uz - (float)iz;
    int b = (ix * Rp1 + iy) * Rp1 + iz;
    float v000 = g[4*b],            v001 = g[4*(b+1)];
    float v010 = g[4*(b+Rp1)],      v011 = g[4*(b+Rp1+1)];
    float v100 = g[4*(b+SX)],       v101 = g[4*(b+SX+1)];
    float v110 = g[4*(b+SX+Rp1)],   v111 = g[4*(b+SX+Rp1+1)];
    float c00 = fmaf(fz, v001 - v000, v000);
    float c01 = fmaf(fz, v011 - v010, v010);
    float c10 = fmaf(fz, v101 - v100, v100);
    float c11 = fmaf(fz, v111 - v110, v110);
    float c0  = fmaf(fy, c01 - c00, c00);
    float c1  = fmaf(fy, c11 - c10, c10);
    return fmaf(fx, c1 - c0, c0);
}

// ---------- prep: combined logit pair-table, x-adjacent layout ----------
// Pf[4*jj + c], jj = (iy*33 + iz)*33 + ix, c -> (dy,dz) in {(0,0),(0,1),(1,0),(1,1)}
// value = bl + wl0*L0 + wl1*L1 + wl2*L2 at lattice (ix, iy+dy, iz+dz) (clamped)
__global__ __launch_bounds__(256)
void prep_kernel(const float* __restrict__ g0, const float* __restrict__ g1,
                 const float* __restrict__ g2, const float* __restrict__ wl,
                 const float* __restrict__ bl, float* __restrict__ Pf) {
    int id = blockIdx.x * blockDim.x + threadIdx.x;
    if (id >= NPREP) return;
    int c  = id & 3;
    int jj = id >> 2;
    int ix = jj % L33;
    int r  = jj / L33;
    int iz = r % L33;
    int iy = r / L33;
    int jy = min(iy + (c >> 1), L33 - 1);
    int jz = min(iz + (c & 1),  L33 - 1);
    float fx = (float)ix, fy = (float)jy, fz = (float)jz;
    float L0 = tri_label<8 >(g0, fx * 0.25f, fy * 0.25f, fz * 0.25f);  // exact quarters
    float L1 = tri_label<16>(g1, fx * 0.5f,  fy * 0.5f,  fz * 0.5f);   // exact halves
    float L2 = g2[4 * ((ix * L33 + jy) * L33 + jz)];
    Pf[id] = bl[0] + wl[0] * L0 + wl[1] * L1 + wl[2] * L2;
}

// ---------- RGB corner contribution (1 point per ray, corner-parallel) ----------
template<int R>
__device__ __forceinline__ void rgb_corner(const float* __restrict__ g,
                                           float cx, float cy, float cz,
                                           int dx, int dy, int dz,
                                           float* f3) {
    constexpr int Rp1 = R + 1;
    float ux = cx * (float)R, uy = cy * (float)R, uz = cz * (float)R;
    int ix = min((int)ux, R - 1);
    int iy = min((int)uy, R - 1);
    int iz = min((int)uz, R - 1);
    float fx = ux - (float)ix, fy = uy - (float)iy, fz = uz - (float)iz;
    int idx = ((ix + dx) * Rp1 + (iy + dy)) * Rp1 + (iz + dz);
    float w = (dx ? fx : 1.0f - fx) * (dy ? fy : 1.0f - fy) * (dz ? fz : 1.0f - fz);
    float4 v = *reinterpret_cast<const float4*>(g + 4 * idx);
    f3[0] = w * v.y;
    f3[1] = w * v.z;
    f3[2] = w * v.w;
}

// ---------- main: 8 lanes/ray; iter i covers points 8i..8i+7 (consecutive
// across lanes -> shared cache lines); fully unrolled load pipeline ----------
__global__ __launch_bounds__(256, 4)
void rays_kernel(const float* __restrict__ x,
                 const float4* __restrict__ P,
                 const float* __restrict__ g0,
                 const float* __restrict__ g1,
                 const float* __restrict__ g2,
                 const float* __restrict__ wr,
                 const float* __restrict__ br,
                 float* __restrict__ out_hits,
                 float* __restrict__ out_rgb,
                 int n)
{
    const int tid = blockIdx.x * blockDim.x + threadIdx.x;
    const int ray = tid >> 3;
    const int sub = (int)(threadIdx.x & 7);
    if (ray >= n) return;

    const float th1 = x[ray * 4 + 0];
    const float ph1 = x[ray * 4 + 1];
    const float th2 = x[ray * 4 + 2];
    const float ph2 = x[ray * 4 + 3];
    float s1 = __sinf(th1), c1 = __cosf(th1);
    float s2 = __sinf(th2), c2 = __cosf(th2);
    float p1x = s1 * __cosf(ph1), p1y = s1 * __sinf(ph1), p1z = c1;
    float p2x = s2 * __cosf(ph2), p2y = s2 * __sinf(ph2), p2z = c2;
    const float dxr = p2x - p1x, dyr = p2y - p1y, dzr = p2z - p1z;

    const float inv = 1.0f / (float)(NPTS - 1);
    const float sc  = 16.0f * inv;

    // u(t) = (p+1)*16 ; u in [0,32] (+/- 1 ulp), indices clamped below
    const float bx = fmaf(p1x, 16.0f, 16.0f);
    const float by = fmaf(p1y, 16.0f, 16.0f);
    const float bz = fmaf(p1z, 16.0f, 16.0f);
    const float dux = dxr * sc, duy = dyr * sc, duz = dzr * sc;

    const float subf = (float)sub;
    float maxlogit = -INFINITY;
    int firsthit = NPTS;

#pragma unroll
    for (int i = 0; i < 25; ++i) {
        float tf = subf + (float)(8 * i);    // exact small ints
        float ux = fmaf(tf, dux, bx);
        float uy = fmaf(tf, duy, by);
        float uz = fmaf(tf, duz, bz);
        int ix = min((int)ux, 31);
        int iy = min((int)uy, 31);
        int iz = min((int)uz, 31);
        float fx = ux - (float)ix;
        float fy = uy - (float)iy;
        float fz = uz - (float)iz;
        int jj = (iy * L33 + iz) * L33 + ix;
        const float4* p = P + jj;
        float4 q0 = p[0];
        float4 q1 = p[1];                    // same 64B line 75% of the time
        float mx = fmaf(fx, q1.x - q0.x, q0.x);
        float my = fmaf(fx, q1.y - q0.y, q0.y);
        float mz = fmaf(fx, q1.z - q0.z, q0.z);
        float mw = fmaf(fx, q1.w - q0.w, q0.w);
        float r0 = fmaf(fz, my - mx, mx);
        float r1 = fmaf(fz, mw - mz, mz);
        float logit = fmaf(fy, r1 - r0, r0);
        maxlogit = fmaxf(maxlogit, logit);
        if (logit > 0.0f) firsthit = min(firsthit, 8 * i + sub);
    }

#pragma unroll
    for (int m = 4; m >= 1; m >>= 1) {
        maxlogit = fmaxf(maxlogit, __shfl_xor(maxlogit, m, 64));
        firsthit = min(firsthit, __shfl_xor(firsthit, m, 64));
    }

    // ---- RGB at first-hit point, corner-parallel across the 8 lanes ----
    const int tsel = (firsthit >= NPTS) ? 0 : firsthit;
    {
        float tt = (float)tsel * inv;
        float px = fmaf(dxr, tt, p1x);
        float py = fmaf(dyr, tt, p1y);
        float pz = fmaf(dzr, tt, p1z);
        float cx = fminf(fmaxf(fmaf(px, 0.5f, 0.5f), 0.0f), 1.0f);
        float cy = fminf(fmaxf(fmaf(py, 0.5f, 0.5f), 0.0f), 1.0f);
        float cz = fminf(fmaxf(fmaf(pz, 0.5f, 0.5f), 0.0f), 1.0f);
        const int dx = (sub >> 2) & 1, dy = (sub >> 1) & 1, dz = sub & 1;
        float feat[9];
        rgb_corner<8 >(g0, cx, cy, cz, dx, dy, dz, &feat[0]);
        rgb_corner<16>(g1, cx, cy, cz, dx, dy, dz, &feat[3]);
        rgb_corner<32>(g2, cx, cy, cz, dx, dy, dz, &feat[6]);
        // per-lane partial matmul (linear => sum of per-corner partial products)
        float acc[3];
#pragma unroll
        for (int c = 0; c < 3; ++c) {
            float a = 0.0f;
#pragma unroll
            for (int f = 0; f < 9; ++f) a = fmaf(feat[f], wr[f * 3 + c], a);
            acc[c] = a;
        }
#pragma unroll
        for (int m = 4; m >= 1; m >>= 1) {
#pragma unroll
            for (int c = 0; c < 3; ++c)
                acc[c] += __shfl_xor(acc[c], m, 64);
        }
        if (sub == 0) {
            out_hits[ray] = 1.0f / (1.0f + __expf(-maxlogit));
#pragma unroll
            for (int c = 0; c < 3; ++c)
                out_rgb[ray * 3 + c] = 1.0f / (1.0f + __expf(-(acc[c] + br[c])));
        }
    }
}

extern "C" void kernel_launch(void* const* d_in, const int* in_sizes, int n_in,
                              void* d_out, int out_size, void* d_ws, size_t ws_size,
                              hipStream_t stream) {
    const float* x  = (const float*)d_in[0];
    const float* g0 = (const float*)d_in[1];
    const float* g1 = (const float*)d_in[2];
    const float* g2 = (const float*)d_in[3];
    const float* wl = (const float*)d_in[4];
    const float* bl = (const float*)d_in[5];
    const float* wr = (const float*)d_in[6];
    const float* br = (const float*)d_in[7];

    const int n = in_sizes[0] / 4;
    float* out_hits = (float*)d_out;
    float* out_rgb  = (float*)d_out + n;

    float* Pf = (float*)d_ws;          // NLAT*16 = 574,992 bytes of scratch

    prep_kernel<<<(NPREP + 255) / 256, 256, 0, stream>>>(g0, g1, g2, wl, bl, Pf);

    const int block = 256;             // 32 rays per block
    const int grid = (n * 8 + block - 1) / block;
    rays_kernel<<<grid, block, 0, stream>>>(x, (const float4*)Pf, g0, g1, g2,
                                            wr, br, out_hits, out_rgb, n);
}